// Round 5
// baseline (345.328 us; speedup 1.0000x reference)
//
#include <hip/hip_runtime.h>
#include <math.h>

#define CH 192
#define HW 4096
#define NB 16
#define NELEM (NB*CH*HW)
#define HIDN 768

typedef __bf16 bf16x8 __attribute__((ext_vector_type(8)));
typedef float  f32x4  __attribute__((ext_vector_type(4)));

__device__ __forceinline__ float gelu_f(float v){
    float u = 0.7978845608f * v * (1.0f + 0.044715f*v*v);
    float t = 1.0f - 2.0f/(1.0f + __expf(2.0f*u));
    return 0.5f * v * (1.0f + t);
}
__device__ __forceinline__ float sigmoid_f(float v){
    return 1.0f / (1.0f + __expf(-v));
}
__device__ __forceinline__ unsigned pack2bf(float a, float b){
    union { __bf16 h[2]; unsigned u; } v;
    v.h[0] = (__bf16)a; v.h[1] = (__bf16)b; return v.u;
}
union U8 { bf16x8 v; unsigned u[4]; };

// ---------------- K0: f32 -> bf16 weight conversion
__global__ __launch_bounds__(256) void k_cvt(const float* __restrict__ a,
                                             __bf16* __restrict__ o, int n){
    int i = blockIdx.x*256 + threadIdx.x;
    if (i < n) o[i] = (__bf16)a[i];
}

// ---------------- K1: LN1 + in_proj (192->384). Wave-independent, 32 px/wave, no LDS.
// Operand-swapped MFMA: C[oc][px], A = W rows, B = LN'd activations.
__global__ __launch_bounds__(256, 4) void k_ln_inproj(
    const float* __restrict__ x, const float* __restrict__ lw, const float* __restrict__ lb,
    const __bf16* __restrict__ Wb, const float* __restrict__ bias,
    __bf16* __restrict__ proj, __bf16* __restrict__ gate)
{
    int tid = threadIdx.x;
    int lane = tid & 63;
    int w = tid >> 6;
    int lo = lane & 15, hi = lane >> 4;
    int g0 = (blockIdx.x*4 + w)*32;
    int b = g0 >> 12, pos = g0 & 4095;
    const float* xb = x + (size_t)b*CH*HW + pos;

    bf16x8 afr[2][6];
    #pragma unroll
    for (int pt = 0; pt < 2; ++pt){
        int px = pt*16 + lo;
        float xv[48];
        float s = 0.f, s2 = 0.f;
        #pragma unroll
        for (int ks = 0; ks < 6; ++ks)
            #pragma unroll
            for (int j = 0; j < 8; ++j){
                float v = xb[(size_t)(ks*32 + hi*8 + j)*HW + px];
                xv[ks*8 + j] = v; s += v; s2 += v*v;
            }
        s  += __shfl_xor(s, 16);  s  += __shfl_xor(s, 32);
        s2 += __shfl_xor(s2, 16); s2 += __shfl_xor(s2, 32);
        float mean = s * (1.f/192.f);
        float rstd = rsqrtf(s2 * (1.f/192.f) - mean*mean + 1e-6f);
        #pragma unroll
        for (int ks = 0; ks < 6; ++ks){
            bf16x8 pk;
            #pragma unroll
            for (int j = 0; j < 8; ++j){
                int c = ks*32 + hi*8 + j;
                pk[j] = (__bf16)((xv[ks*8 + j] - mean) * rstd * lw[c] + lb[c]);
            }
            afr[pt][ks] = pk;
        }
    }

    #pragma unroll 1
    for (int nt = 0; nt < 24; ++nt){
        f32x4 a0 = (f32x4){0.f,0.f,0.f,0.f};
        f32x4 a1 = (f32x4){0.f,0.f,0.f,0.f};
        #pragma unroll
        for (int ks = 0; ks < 6; ++ks){
            bf16x8 wf = *(const bf16x8*)(Wb + (size_t)(nt*16 + lo)*CH + ks*32 + hi*8);
            a0 = __builtin_amdgcn_mfma_f32_16x16x32_bf16(wf, afr[0][ks], a0, 0, 0, 0);
            a1 = __builtin_amdgcn_mfma_f32_16x16x32_bf16(wf, afr[1][ks], a1, 0, 0, 0);
        }
        bool isg = (nt >= 12);
        #pragma unroll
        for (int r = 0; r < 4; ++r){
            int ocg = nt*16 + hi*4 + r;
            float bv = bias[ocg];
            float v0 = a0[r] + bv, v1 = a1[r] + bv;
            if (isg){ v0 = sigmoid_f(v0); v1 = sigmoid_f(v1); }
            int oc = isg ? (ocg - CH) : ocg;
            __bf16* dst = isg ? gate : proj;
            size_t idx = (size_t)(b*CH + oc)*HW + pos + lo;
            dst[idx] = (__bf16)v0;
            dst[idx + 16] = (__bf16)v1;
        }
    }
}

// ---------------- K2: fused spatial: dwconv3 + 4-dir scans + local conv3 + gate + BN partials
__global__ __launch_bounds__(256, 3) void k_spatial(
    const __bf16* __restrict__ proj, const __bf16* __restrict__ gate,
    const float* __restrict__ dwk, const float* __restrict__ lek,
    const float* __restrict__ dl, const float* __restrict__ ml, const float* __restrict__ il,
    float* __restrict__ mixed, float* __restrict__ part)
{
    __shared__ float t[66*67];
    __shared__ float r[64*65];
    __shared__ float r2[64*65];
    __shared__ float rs[256], rq[256];
    int tid = threadIdx.x;
    int lane = tid & 63;
    int w = tid >> 6;
    int bc = blockIdx.x;
    int c = bc % CH;
    const __bf16* pp = proj + (size_t)bc*HW;

    for (int i = tid; i < 66*66; i += 256){
        int yy = i / 66, xx = i - yy*66;
        float v = 0.f;
        if (yy >= 1 && yy <= 64 && xx >= 1 && xx <= 64)
            v = (float)pp[(yy-1)*64 + (xx-1)];
        t[yy*67 + xx] = v;
    }
    float d[4], e[4], m[4];
    {
        float lg[4], mx = -1e30f;
        #pragma unroll
        for (int k = 0; k < 4; ++k){ lg[k] = ml[k*CH + c]; mx = fmaxf(mx, lg[k]); }
        float se = 0.f;
        #pragma unroll
        for (int k = 0; k < 4; ++k){ lg[k] = __expf(lg[k]-mx); se += lg[k]; }
        #pragma unroll
        for (int k = 0; k < 4; ++k){
            m[k] = lg[k] / se;
            float dd = sigmoid_f(dl[k*CH + c]);
            dd = fminf(fmaxf(dd, 0.05f), 0.995f);
            d[k] = dd;
            e[k] = (1.0f - dd) * (1.0f + tanhf(il[k*CH + c]));
        }
    }
    __syncthreads();
    float kk[9];
    #pragma unroll
    for (int j = 0; j < 9; ++j) kk[j] = dwk[c*9 + j];
    float dw[16];
    #pragma unroll
    for (int j = 0; j < 16; ++j){
        int i = tid + j*256;
        int y = i >> 6, xx = i & 63;
        float sv = 0.f;
        #pragma unroll
        for (int dy = 0; dy < 3; ++dy)
            #pragma unroll
            for (int dx = 0; dx < 3; ++dx)
                sv = fmaf(kk[dy*3+dx], t[(y+dy)*67 + xx + dx], sv);
        dw[j] = sv;
    }
    __syncthreads();
    #pragma unroll
    for (int j = 0; j < 16; ++j){
        int i = tid + j*256;
        t[((i>>6)+1)*67 + (i & 63) + 1] = dw[j];
    }
    __syncthreads();
    if (w == 0){
        int y = lane; float s = 0.f;
        for (int xx = 0; xx < 64; ++xx){
            s = fmaf(d[0], s, e[0]*t[(y+1)*67 + xx + 1]);
            r[y*65 + xx] = m[0]*s;
        }
    } else if (w == 1){
        int xx = lane; float s = 0.f;
        for (int y = 0; y < 64; ++y){
            s = fmaf(d[2], s, e[2]*t[(y+1)*67 + xx + 1]);
            r2[y*65 + xx] = m[2]*s;
        }
    }
    __syncthreads();
    if (w == 2){
        int y = lane; float s = 0.f;
        for (int xx = 63; xx >= 0; --xx){
            s = fmaf(d[1], s, e[1]*t[(y+1)*67 + xx + 1]);
            r[y*65 + xx] += m[1]*s;
        }
    } else if (w == 3){
        int xx = lane; float s = 0.f;
        for (int y = 63; y >= 0; --y){
            s = fmaf(d[3], s, e[3]*t[(y+1)*67 + xx + 1]);
            r2[y*65 + xx] += m[3]*s;
        }
    }
    __syncthreads();
    float lk[9];
    #pragma unroll
    for (int j = 0; j < 9; ++j) lk[j] = lek[c*9 + j];
    const __bf16* gp = gate + (size_t)bc*HW;
    float* mp = mixed + (size_t)bc*HW;
    float s1 = 0.f, s2 = 0.f;
    #pragma unroll
    for (int j = 0; j < 16; ++j){
        int i = tid + j*256;
        int y = i >> 6, xx = i & 63;
        float sv = 0.f;
        #pragma unroll
        for (int dy = 0; dy < 3; ++dy)
            #pragma unroll
            for (int dx = 0; dx < 3; ++dx)
                sv = fmaf(lk[dy*3+dx], t[(y+dy)*67 + xx + dx], sv);
        float mv = (r[y*65 + xx] + r2[y*65 + xx] + sv) * (float)gp[i];
        mp[i] = mv;
        s1 += mv; s2 += mv*mv;
    }
    rs[tid] = s1; rq[tid] = s2;
    __syncthreads();
    for (int off = 128; off > 0; off >>= 1){
        if (tid < off){ rs[tid] += rs[tid+off]; rq[tid] += rq[tid+off]; }
        __syncthreads();
    }
    if (tid == 0){ part[bc] = rs[0]; part[NB*CH + bc] = rq[0]; }
}

// ---------------- K2b: finalize BN scale/shift per channel (deterministic)
__global__ __launch_bounds__(192) void k_bn_final(
    const float* __restrict__ part, const float* __restrict__ bw,
    const float* __restrict__ bb, float* __restrict__ bnp)
{
    int c = threadIdx.x;
    float S = 0.f, Q = 0.f;
    for (int b = 0; b < NB; ++b){
        S += part[b*CH + c];
        Q += part[NB*CH + b*CH + c];
    }
    float mean = S * (1.f/65536.f);
    float var  = Q * (1.f/65536.f) - mean*mean;
    float sc = bw[c] * rsqrtf(var + 1e-5f);
    bnp[c] = sc;
    bnp[CH + c] = bb[c] - mean * sc;
}

// ---------------- K3: BN+GELU + out_proj (192->192) + residual. Wave-independent, no LDS.
__global__ __launch_bounds__(256, 4) void k_outproj(
    const float* __restrict__ mixed, const float* __restrict__ bnp,
    const __bf16* __restrict__ Wb, const float* __restrict__ bias,
    const float* __restrict__ x, float* __restrict__ xr)
{
    int tid = threadIdx.x;
    int lane = tid & 63;
    int w = tid >> 6;
    int lo = lane & 15, hi = lane >> 4;
    int g0 = (blockIdx.x*4 + w)*32;
    int b = g0 >> 12, pos = g0 & 4095;
    const float* mb = mixed + (size_t)b*CH*HW + pos;

    bf16x8 afr[2][6];
    #pragma unroll
    for (int pt = 0; pt < 2; ++pt){
        int px = pt*16 + lo;
        #pragma unroll
        for (int ks = 0; ks < 6; ++ks){
            bf16x8 pk;
            #pragma unroll
            for (int j = 0; j < 8; ++j){
                int c = ks*32 + hi*8 + j;
                float v = mb[(size_t)c*HW + px];
                pk[j] = (__bf16)gelu_f(fmaf(v, bnp[c], bnp[CH + c]));
            }
            afr[pt][ks] = pk;
        }
    }

    const float* xbb = x + (size_t)b*CH*HW + pos;
    float* xrb = xr + (size_t)b*CH*HW + pos;
    #pragma unroll 1
    for (int nt = 0; nt < 12; ++nt){
        f32x4 a0 = (f32x4){0.f,0.f,0.f,0.f};
        f32x4 a1 = (f32x4){0.f,0.f,0.f,0.f};
        #pragma unroll
        for (int ks = 0; ks < 6; ++ks){
            bf16x8 wf = *(const bf16x8*)(Wb + (size_t)(nt*16 + lo)*CH + ks*32 + hi*8);
            a0 = __builtin_amdgcn_mfma_f32_16x16x32_bf16(wf, afr[0][ks], a0, 0, 0, 0);
            a1 = __builtin_amdgcn_mfma_f32_16x16x32_bf16(wf, afr[1][ks], a1, 0, 0, 0);
        }
        #pragma unroll
        for (int r = 0; r < 4; ++r){
            int oc = nt*16 + hi*4 + r;
            float bv = bias[oc];
            size_t idx = (size_t)oc*HW + lo;
            xrb[idx]      = xbb[idx]      + bv + a0[r];
            xrb[idx + 16] = xbb[idx + 16] + bv + a1[r];
        }
    }
}

// ---------------- K4: LN2 + fc1 + GELU + fc2 + residual. Wave-independent, 32 px/wave,
// no LDS, no barriers; fc1->fc2 relayout via in-wave shuffles.
__global__ __launch_bounds__(256, 2) void k_mlp(
    const float* __restrict__ lw, const float* __restrict__ lb,
    const __bf16* __restrict__ w1b, const float* __restrict__ b1,
    const __bf16* __restrict__ w2b, const float* __restrict__ b2,
    float* io)
{
    int tid = threadIdx.x;
    int lane = tid & 63;
    int w = tid >> 6;
    int lo = lane & 15, hi = lane >> 4;
    int g0 = (blockIdx.x*4 + w)*32;
    int b = g0 >> 12, pos = g0 & 4095;
    float* iob = io + (size_t)b*CH*HW + pos;

    // LN2 -> B-fragments in registers
    bf16x8 afr[2][6];
    #pragma unroll
    for (int pt = 0; pt < 2; ++pt){
        int px = pt*16 + lo;
        float xv[48];
        float s = 0.f, s2 = 0.f;
        #pragma unroll
        for (int ks = 0; ks < 6; ++ks)
            #pragma unroll
            for (int j = 0; j < 8; ++j){
                float v = iob[(size_t)(ks*32 + hi*8 + j)*HW + px];
                xv[ks*8 + j] = v; s += v; s2 += v*v;
            }
        s  += __shfl_xor(s, 16);  s  += __shfl_xor(s, 32);
        s2 += __shfl_xor(s2, 16); s2 += __shfl_xor(s2, 32);
        float mean = s * (1.f/192.f);
        float rstd = rsqrtf(s2 * (1.f/192.f) - mean*mean + 1e-6f);
        #pragma unroll
        for (int ks = 0; ks < 6; ++ks){
            bf16x8 pk;
            #pragma unroll
            for (int j = 0; j < 8; ++j){
                int c = ks*32 + hi*8 + j;
                pk[j] = (__bf16)((xv[ks*8 + j] - mean) * rstd * lw[c] + lb[c]);
            }
            afr[pt][ks] = pk;
        }
    }

    f32x4 acc2[12][2];
    #pragma unroll
    for (int nt2 = 0; nt2 < 12; ++nt2){
        acc2[nt2][0] = (f32x4){0.f,0.f,0.f,0.f};
        acc2[nt2][1] = (f32x4){0.f,0.f,0.f,0.f};
    }

    #pragma unroll 1
    for (int ch = 0; ch < 24; ++ch){
        int hb = ch*32;
        // fc1: two 16-hidden tiles (g=0,1), both pixel tiles
        f32x4 a1[2][2];
        #pragma unroll
        for (int g = 0; g < 2; ++g){
            a1[g][0] = (f32x4){0.f,0.f,0.f,0.f};
            a1[g][1] = (f32x4){0.f,0.f,0.f,0.f};
        }
        #pragma unroll
        for (int ks = 0; ks < 6; ++ks){
            #pragma unroll
            for (int g = 0; g < 2; ++g){
                bf16x8 wf = *(const bf16x8*)(w1b + (size_t)(hb + g*16 + lo)*CH + ks*32 + hi*8);
                a1[g][0] = __builtin_amdgcn_mfma_f32_16x16x32_bf16(wf, afr[0][ks], a1[g][0], 0, 0, 0);
                a1[g][1] = __builtin_amdgcn_mfma_f32_16x16x32_bf16(wf, afr[1][ks], a1[g][1], 0, 0, 0);
            }
        }
        float bA[4], bB[4];
        #pragma unroll
        for (int r = 0; r < 4; ++r){
            bA[r] = b1[hb + hi*4 + r];
            bB[r] = b1[hb + 16 + hi*4 + r];
        }
        // bias + gelu + pack + in-wave transpose -> fc2 B-fragments
        U8 b2f[2];
        #pragma unroll
        for (int pt = 0; pt < 2; ++pt){
            unsigned uA0 = pack2bf(gelu_f(a1[0][pt][0] + bA[0]), gelu_f(a1[0][pt][1] + bA[1]));
            unsigned uA1 = pack2bf(gelu_f(a1[0][pt][2] + bA[2]), gelu_f(a1[0][pt][3] + bA[3]));
            unsigned uB0 = pack2bf(gelu_f(a1[1][pt][0] + bB[0]), gelu_f(a1[1][pt][1] + bB[1]));
            unsigned uB1 = pack2bf(gelu_f(a1[1][pt][2] + bB[2]), gelu_f(a1[1][pt][3] + bB[3]));
            int s0 = lo + ((hi & 1) << 5);
            int s1 = s0 + 16;
            unsigned t0 = __shfl(uA0, s0), t1 = __shfl(uA1, s0);
            unsigned t2 = __shfl(uA0, s1), t3 = __shfl(uA1, s1);
            unsigned q0 = __shfl(uB0, s0), q1 = __shfl(uB1, s0);
            unsigned q2 = __shfl(uB0, s1), q3 = __shfl(uB1, s1);
            bool ub = (hi >= 2);
            b2f[pt].u[0] = ub ? q0 : t0;
            b2f[pt].u[1] = ub ? q1 : t1;
            b2f[pt].u[2] = ub ? q2 : t2;
            b2f[pt].u[3] = ub ? q3 : t3;
        }
        // fc2 partial over this 32-hidden chunk
        #pragma unroll
        for (int nt2 = 0; nt2 < 12; ++nt2){
            bf16x8 wf2 = *(const bf16x8*)(w2b + (size_t)(nt2*16 + lo)*HIDN + hb + hi*8);
            acc2[nt2][0] = __builtin_amdgcn_mfma_f32_16x16x32_bf16(wf2, b2f[0].v, acc2[nt2][0], 0, 0, 0);
            acc2[nt2][1] = __builtin_amdgcn_mfma_f32_16x16x32_bf16(wf2, b2f[1].v, acc2[nt2][1], 0, 0, 0);
        }
    }

    // epilogue: residual RMW
    #pragma unroll
    for (int nt2 = 0; nt2 < 12; ++nt2){
        #pragma unroll
        for (int r = 0; r < 4; ++r){
            int oc = nt2*16 + hi*4 + r;
            float bv = b2[oc];
            size_t idx = (size_t)oc*HW + lo;
            iob[idx]      += bv + acc2[nt2][0][r];
            iob[idx + 16] += bv + acc2[nt2][1][r];
        }
    }
}

extern "C" void kernel_launch(void* const* d_in, const int* in_sizes, int n_in,
                              void* d_out, int out_size, void* d_ws, size_t ws_size,
                              hipStream_t stream) {
    const float* x    = (const float*)d_in[0];
    const float* ln1w = (const float*)d_in[1];
    const float* ln1b = (const float*)d_in[2];
    const float* ipw  = (const float*)d_in[3];
    const float* ipb  = (const float*)d_in[4];
    const float* dwk  = (const float*)d_in[5];
    const float* lek  = (const float*)d_in[6];
    const float* dlg  = (const float*)d_in[7];
    const float* mlg  = (const float*)d_in[8];
    const float* isc  = (const float*)d_in[9];
    const float* bnw  = (const float*)d_in[10];
    const float* bnb  = (const float*)d_in[11];
    const float* opw  = (const float*)d_in[12];
    const float* opb  = (const float*)d_in[13];
    const float* ln2w = (const float*)d_in[14];
    const float* ln2b = (const float*)d_in[15];
    const float* f1w  = (const float*)d_in[16];
    const float* f1b  = (const float*)d_in[17];
    const float* f2w  = (const float*)d_in[18];
    const float* f2b  = (const float*)d_in[19];

    float* out = (float*)d_out;
    __bf16* bufP = (__bf16*)d_ws;                      // proj bf16
    __bf16* bufG = bufP + (size_t)NELEM;               // gate bf16
    float* bufM = (float*)(bufG + (size_t)NELEM);      // mixed f32
    float* part = bufM + (size_t)NELEM;
    float* bnp  = part + 2*NB*CH;
    __bf16* ipwb = (__bf16*)(bnp + 2*CH);
    __bf16* opwb = ipwb + (size_t)2*CH*CH;
    __bf16* w1b  = opwb + (size_t)CH*CH;
    __bf16* w2b  = w1b  + (size_t)HIDN*CH;

    k_cvt<<<(2*CH*CH + 255)/256, 256, 0, stream>>>(ipw, ipwb, 2*CH*CH);
    k_cvt<<<(CH*CH + 255)/256, 256, 0, stream>>>(opw, opwb, CH*CH);
    k_cvt<<<(HIDN*CH + 255)/256, 256, 0, stream>>>(f1w, w1b, HIDN*CH);
    k_cvt<<<(HIDN*CH + 255)/256, 256, 0, stream>>>(f2w, w2b, CH*HIDN);

    k_ln_inproj<<<512, 256, 0, stream>>>(x, ln1w, ln1b, ipwb, ipb, bufP, bufG);
    k_spatial  <<<NB*CH, 256, 0, stream>>>(bufP, bufG, dwk, lek, dlg, mlg, isc, bufM, part);
    k_bn_final <<<1, 192, 0, stream>>>(part, bnw, bnb, bnp);
    k_outproj  <<<512, 256, 0, stream>>>(bufM, bnp, opwb, opb, x, out);
    k_mlp      <<<512, 256, 0, stream>>>(ln2w, ln2b, w1b, f1b, w2b, f2b, out);
}

// Round 6
// 235.852 us; speedup vs baseline: 1.4642x; 1.4642x over previous
//
#include <hip/hip_runtime.h>
#include <math.h>

#define CH 192
#define HW 4096
#define NB 16
#define NELEM (NB*CH*HW)
#define HIDN 768

typedef __bf16 bf16x8 __attribute__((ext_vector_type(8)));
typedef float  f32x4  __attribute__((ext_vector_type(4)));

__device__ __forceinline__ float gelu_f(float v){
    float u = 0.7978845608f * v * (1.0f + 0.044715f*v*v);
    float t = 1.0f - 2.0f/(1.0f + __expf(2.0f*u));
    return 0.5f * v * (1.0f + t);
}
__device__ __forceinline__ float sigmoid_f(float v){
    return 1.0f / (1.0f + __expf(-v));
}
__device__ __forceinline__ unsigned pack2bf(float a, float b){
    union { __bf16 h[2]; unsigned u; } v;
    v.h[0] = (__bf16)a; v.h[1] = (__bf16)b; return v.u;
}
union U8 { bf16x8 v; unsigned u[4]; };

__device__ __forceinline__ void gload16(const void* g, void* l){
    __builtin_amdgcn_global_load_lds(
        (const __attribute__((address_space(1))) unsigned*)g,
        (__attribute__((address_space(3))) unsigned*)l, 16, 0, 0);
}

// ---------------- K0: f32 -> bf16 weight conversion
__global__ __launch_bounds__(256) void k_cvt(const float* __restrict__ a,
                                             __bf16* __restrict__ o, int n){
    int i = blockIdx.x*256 + threadIdx.x;
    if (i < n) o[i] = (__bf16)a[i];
}

// ---------------- K1: LN1 + in_proj (192->384) via bf16 MFMA (round-4 LDS structure)
__global__ __launch_bounds__(256, 3) void k_ln_inproj(
    const float* __restrict__ x, const float* __restrict__ lw, const float* __restrict__ lb,
    const __bf16* __restrict__ Wb, const float* __restrict__ bias,
    __bf16* __restrict__ proj, __bf16* __restrict__ gate)
{
    __shared__ __align__(16) unsigned char smem[24576 + 2560 + 25344];
    __bf16* h2s = (__bf16*)smem;                       // 192*64 frag-linear
    float* redS = (float*)(smem + 24576);
    float* redQ = redS + 256;
    float* mS   = redQ + 256;
    float* rS   = mS + 64;
    __bf16* outb = (__bf16*)(smem + 27136);            // 192*66 bf16 bounce

    int tid = threadIdx.x;
    int lane = tid & 63;
    int w = tid >> 6;
    int lo = lane & 15, hi = lane >> 4;
    int bid = blockIdx.x;
    int b = bid >> 6;
    int p0 = (bid & 63) << 6;
    const float* xb = x + (size_t)b*CH*HW + p0;
    int px = lane;

    float xv[48];
    float s = 0.f, s2 = 0.f;
    #pragma unroll
    for (int k = 0; k < 48; ++k){
        float v = xb[(size_t)(48*w + k)*HW + px];
        xv[k] = v; s += v; s2 += v*v;
    }
    redS[tid] = s; redQ[tid] = s2;
    __syncthreads();
    if (tid < 64){
        float S = redS[tid]+redS[tid+64]+redS[tid+128]+redS[tid+192];
        float Q = redQ[tid]+redQ[tid+64]+redQ[tid+128]+redQ[tid+192];
        float mean = S * (1.f/192.f);
        float var  = Q * (1.f/192.f) - mean*mean;
        mS[tid] = mean;
        rS[tid] = rsqrtf(var + 1e-6f);
    }
    __syncthreads();
    {
        float mean = mS[px], rstd = rS[px];
        #pragma unroll
        for (int m = 0; m < 6; ++m){
            int c8 = 48*w + 8*m;
            int ks = c8 >> 5, hh = (c8 >> 3) & 3;
            bf16x8 pk;
            #pragma unroll
            for (int j = 0; j < 8; ++j){
                int c = c8 + j;
                pk[j] = (__bf16)((xv[8*m + j] - mean) * rstd * lw[c] + lb[c]);
            }
            *(bf16x8*)(h2s + (((px>>4)*6 + ks)*64 + hh*16 + (px & 15))*8) = pk;
        }
    }
    __syncthreads();

    #pragma unroll
    for (int g = 0; g < 2; ++g){
        f32x4 acc[3][4];
        #pragma unroll
        for (int nt = 0; nt < 3; ++nt)
            #pragma unroll
            for (int pt = 0; pt < 4; ++pt)
                acc[nt][pt] = (f32x4){0.f,0.f,0.f,0.f};
        #pragma unroll
        for (int ks = 0; ks < 6; ++ks){
            bf16x8 a[4];
            #pragma unroll
            for (int pt = 0; pt < 4; ++pt)
                a[pt] = *(const bf16x8*)(h2s + ((pt*6 + ks)*64 + lane)*8);
            #pragma unroll
            for (int nt = 0; nt < 3; ++nt){
                bf16x8 bf = *(const bf16x8*)
                    (Wb + (size_t)(g*192 + w*48 + nt*16 + lo)*CH + ks*32 + hi*8);
                #pragma unroll
                for (int pt = 0; pt < 4; ++pt)
                    acc[nt][pt] = __builtin_amdgcn_mfma_f32_16x16x32_bf16(
                        a[pt], bf, acc[nt][pt], 0, 0, 0);
            }
        }
        #pragma unroll
        for (int nt = 0; nt < 3; ++nt){
            int ocl = w*48 + nt*16 + lo;
            float bv = bias[g*CH + ocl];
            #pragma unroll
            for (int pt = 0; pt < 4; ++pt)
                #pragma unroll
                for (int r = 0; r < 4; ++r){
                    float v = acc[nt][pt][r] + bv;
                    if (g == 1) v = sigmoid_f(v);
                    outb[ocl*66 + pt*16 + hi*4 + r] = (__bf16)v;
                }
        }
        __syncthreads();
        __bf16* dst = (g == 0) ? proj : gate;
        for (int i = tid; i < CH*64; i += 256){
            int c = i >> 6, p = i & 63;
            dst[(size_t)(b*CH + c)*HW + p0 + p] = outb[c*66 + p];
        }
        __syncthreads();
    }
}

// ---------------- K2: fused spatial: dwconv3 + 4-dir scans + local conv3 + gate + BN partials
__global__ __launch_bounds__(256, 3) void k_spatial(
    const __bf16* __restrict__ proj, const __bf16* __restrict__ gate,
    const float* __restrict__ dwk, const float* __restrict__ lek,
    const float* __restrict__ dl, const float* __restrict__ ml, const float* __restrict__ il,
    float* __restrict__ mixed, float* __restrict__ part)
{
    __shared__ float t[66*67];
    __shared__ float r[64*65];
    __shared__ float r2[64*65];
    __shared__ float rs[256], rq[256];
    int tid = threadIdx.x;
    int lane = tid & 63;
    int w = tid >> 6;
    int bc = blockIdx.x;
    int c = bc % CH;
    const __bf16* pp = proj + (size_t)bc*HW;

    for (int i = tid; i < 66*66; i += 256){
        int yy = i / 66, xx = i - yy*66;
        float v = 0.f;
        if (yy >= 1 && yy <= 64 && xx >= 1 && xx <= 64)
            v = (float)pp[(yy-1)*64 + (xx-1)];
        t[yy*67 + xx] = v;
    }
    float d[4], e[4], m[4];
    {
        float lg[4], mx = -1e30f;
        #pragma unroll
        for (int k = 0; k < 4; ++k){ lg[k] = ml[k*CH + c]; mx = fmaxf(mx, lg[k]); }
        float se = 0.f;
        #pragma unroll
        for (int k = 0; k < 4; ++k){ lg[k] = __expf(lg[k]-mx); se += lg[k]; }
        #pragma unroll
        for (int k = 0; k < 4; ++k){
            m[k] = lg[k] / se;
            float dd = sigmoid_f(dl[k*CH + c]);
            dd = fminf(fmaxf(dd, 0.05f), 0.995f);
            d[k] = dd;
            e[k] = (1.0f - dd) * (1.0f + tanhf(il[k*CH + c]));
        }
    }
    __syncthreads();
    float kk[9];
    #pragma unroll
    for (int j = 0; j < 9; ++j) kk[j] = dwk[c*9 + j];
    float dw[16];
    #pragma unroll
    for (int j = 0; j < 16; ++j){
        int i = tid + j*256;
        int y = i >> 6, xx = i & 63;
        float sv = 0.f;
        #pragma unroll
        for (int dy = 0; dy < 3; ++dy)
            #pragma unroll
            for (int dx = 0; dx < 3; ++dx)
                sv = fmaf(kk[dy*3+dx], t[(y+dy)*67 + xx + dx], sv);
        dw[j] = sv;
    }
    __syncthreads();
    #pragma unroll
    for (int j = 0; j < 16; ++j){
        int i = tid + j*256;
        t[((i>>6)+1)*67 + (i & 63) + 1] = dw[j];
    }
    __syncthreads();
    if (w == 0){
        int y = lane; float s = 0.f;
        for (int xx = 0; xx < 64; ++xx){
            s = fmaf(d[0], s, e[0]*t[(y+1)*67 + xx + 1]);
            r[y*65 + xx] = m[0]*s;
        }
    } else if (w == 1){
        int xx = lane; float s = 0.f;
        for (int y = 0; y < 64; ++y){
            s = fmaf(d[2], s, e[2]*t[(y+1)*67 + xx + 1]);
            r2[y*65 + xx] = m[2]*s;
        }
    }
    __syncthreads();
    if (w == 2){
        int y = lane; float s = 0.f;
        for (int xx = 63; xx >= 0; --xx){
            s = fmaf(d[1], s, e[1]*t[(y+1)*67 + xx + 1]);
            r[y*65 + xx] += m[1]*s;
        }
    } else if (w == 3){
        int xx = lane; float s = 0.f;
        for (int y = 63; y >= 0; --y){
            s = fmaf(d[3], s, e[3]*t[(y+1)*67 + xx + 1]);
            r2[y*65 + xx] += m[3]*s;
        }
    }
    __syncthreads();
    float lk[9];
    #pragma unroll
    for (int j = 0; j < 9; ++j) lk[j] = lek[c*9 + j];
    const __bf16* gp = gate + (size_t)bc*HW;
    float* mp = mixed + (size_t)bc*HW;
    float s1 = 0.f, s2 = 0.f;
    #pragma unroll
    for (int j = 0; j < 16; ++j){
        int i = tid + j*256;
        int y = i >> 6, xx = i & 63;
        float sv = 0.f;
        #pragma unroll
        for (int dy = 0; dy < 3; ++dy)
            #pragma unroll
            for (int dx = 0; dx < 3; ++dx)
                sv = fmaf(lk[dy*3+dx], t[(y+dy)*67 + xx + dx], sv);
        float mv = (r[y*65 + xx] + r2[y*65 + xx] + sv) * (float)gp[i];
        mp[i] = mv;
        s1 += mv; s2 += mv*mv;
    }
    rs[tid] = s1; rq[tid] = s2;
    __syncthreads();
    for (int off = 128; off > 0; off >>= 1){
        if (tid < off){ rs[tid] += rs[tid+off]; rq[tid] += rq[tid+off]; }
        __syncthreads();
    }
    if (tid == 0){ part[bc] = rs[0]; part[NB*CH + bc] = rq[0]; }
}

// ---------------- K2b: finalize BN scale/shift per channel (deterministic)
__global__ __launch_bounds__(192) void k_bn_final(
    const float* __restrict__ part, const float* __restrict__ bw,
    const float* __restrict__ bb, float* __restrict__ bnp)
{
    int c = threadIdx.x;
    float S = 0.f, Q = 0.f;
    for (int b = 0; b < NB; ++b){
        S += part[b*CH + c];
        Q += part[NB*CH + b*CH + c];
    }
    float mean = S * (1.f/65536.f);
    float var  = Q * (1.f/65536.f) - mean*mean;
    float sc = bw[c] * rsqrtf(var + 1e-5f);
    bnp[c] = sc;
    bnp[CH + c] = bb[c] - mean * sc;
}

// ---------------- K3: BN+GELU + out_proj (192->192) MFMA + residual (round-4 structure)
__global__ __launch_bounds__(256, 3) void k_outproj(
    const float* __restrict__ mixed, const float* __restrict__ bnp,
    const __bf16* __restrict__ Wb, const float* __restrict__ bias,
    const float* __restrict__ x, float* __restrict__ xr)
{
    __shared__ __align__(16) unsigned char smem[34304];
    __bf16* h2s = (__bf16*)smem;
    float* outb = (float*)smem;

    int tid = threadIdx.x;
    int lane = tid & 63;
    int w = tid >> 6;
    int lo = lane & 15, hi = lane >> 4;
    int bid = blockIdx.x;
    int b = bid >> 6;
    int p0 = (bid & 63) << 6;
    const float* mb = mixed + (size_t)b*CH*HW + p0;
    int px = lane;

    #pragma unroll
    for (int m = 0; m < 6; ++m){
        int c8 = 48*w + 8*m;
        int ks = c8 >> 5, hh = (c8 >> 3) & 3;
        bf16x8 pk;
        #pragma unroll
        for (int j = 0; j < 8; ++j){
            int c = c8 + j;
            float v = mb[(size_t)c*HW + px];
            pk[j] = (__bf16)gelu_f(fmaf(v, bnp[c], bnp[CH + c]));
        }
        *(bf16x8*)(h2s + (((px>>4)*6 + ks)*64 + hh*16 + (px & 15))*8) = pk;
    }
    __syncthreads();

    f32x4 acc[3][4];
    #pragma unroll
    for (int nt = 0; nt < 3; ++nt)
        #pragma unroll
        for (int pt = 0; pt < 4; ++pt)
            acc[nt][pt] = (f32x4){0.f,0.f,0.f,0.f};
    #pragma unroll
    for (int ks = 0; ks < 6; ++ks){
        bf16x8 a[4];
        #pragma unroll
        for (int pt = 0; pt < 4; ++pt)
            a[pt] = *(const bf16x8*)(h2s + ((pt*6 + ks)*64 + lane)*8);
        #pragma unroll
        for (int nt = 0; nt < 3; ++nt){
            bf16x8 bf = *(const bf16x8*)
                (Wb + (size_t)(w*48 + nt*16 + lo)*CH + ks*32 + hi*8);
            #pragma unroll
            for (int pt = 0; pt < 4; ++pt)
                acc[nt][pt] = __builtin_amdgcn_mfma_f32_16x16x32_bf16(
                    a[pt], bf, acc[nt][pt], 0, 0, 0);
        }
    }
    __syncthreads();

    const float* xbb = x + (size_t)b*CH*HW + p0;
    float* xrb = xr + (size_t)b*CH*HW + p0;
    #pragma unroll
    for (int nt = 0; nt < 2; ++nt){
        int cc = w*32 + nt*16 + lo;
        #pragma unroll
        for (int pt = 0; pt < 4; ++pt)
            #pragma unroll
            for (int r = 0; r < 4; ++r)
                outb[cc*67 + pt*16 + hi*4 + r] = acc[nt][pt][r];
    }
    __syncthreads();
    for (int i = tid; i < 128*64; i += 256){
        int cc = i >> 6, p = i & 63;
        int c = (cc >> 5)*48 + (cc & 31);
        size_t idx = (size_t)c*HW + p;
        xrb[idx] = xbb[idx] + bias[c] + outb[cc*67 + p];
    }
    __syncthreads();
    {
        int cc = w*16 + lo;
        #pragma unroll
        for (int pt = 0; pt < 4; ++pt)
            #pragma unroll
            for (int r = 0; r < 4; ++r)
                outb[cc*67 + pt*16 + hi*4 + r] = acc[2][pt][r];
    }
    __syncthreads();
    for (int i = tid; i < 64*64; i += 256){
        int cc = i >> 6, p = i & 63;
        int c = (cc >> 4)*48 + 32 + (cc & 15);
        size_t idx = (size_t)c*HW + p;
        xrb[idx] = xbb[idx] + bias[c] + outb[cc*67 + p];
    }
}

// ---------------- K4: LN2 + fc1 + GELU + fc2 + residual.
// v3: activations in registers (32 px/wave, 128 px/block); weights double-buffered
// in LDS via global_load_lds (2-phase pipeline, 1 barrier per 32-hidden chunk).
__global__ __launch_bounds__(256, 2) void k_mlp(
    const float* __restrict__ lw, const float* __restrict__ lb,
    const __bf16* __restrict__ w1b, const float* __restrict__ b1,
    const __bf16* __restrict__ w2b, const float* __restrict__ b2,
    float* io)
{
    // chunk buffer: w1c [32h][192k] rows padded to 400B @0 (13312B incl. pad),
    //               w2c [192oc][32h] rows padded to 80B @13312 (15360B). stride 28672.
    __shared__ __align__(16) unsigned char smem[2*28672];
    int tid = threadIdx.x;
    int lane = tid & 63;
    int w = tid >> 6;
    int lo = lane & 15, hi = lane >> 4;
    int g0 = blockIdx.x*128;
    int b = g0 >> 12, pos = g0 & 4095;
    float* iob = io + (size_t)b*CH*HW + pos + w*32;   // this wave's 32 pixels

    // staging descriptors: 28 wave-issues of 1024B per chunk, 7 per wave
    const char* srcP[7]; int dstO[7]; int stepO[7];
    #pragma unroll
    for (int k = 0; k < 7; ++k){
        int g = w*7 + k;
        if (g < 13){
            int doff = g*1024 + lane*16;
            int rr = doff/400;
            int q = (doff - rr*400) >> 4;
            bool ok = (doff < 12800) && (q < 24);
            dstO[k] = doff;
            srcP[k] = (const char*)w1b + (ok ? (rr*384 + q*16) : 0);
            stepO[k] = ok ? 12288 : 0;           // 32 rows * 384B per chunk
        } else {
            int doff = (g-13)*1024 + lane*16;
            int oc = doff/80;
            int q = (doff - oc*80) >> 4;
            bool ok = (q < 4);
            dstO[k] = 13312 + doff;
            srcP[k] = (const char*)w2b + (ok ? (oc*1536 + q*16) : 0);
            stepO[k] = ok ? 64 : 0;              // 32 h * 2B per chunk
        }
    }
    // stage chunk 0 -> buf0 (flies under the LN2 loads)
    #pragma unroll
    for (int k = 0; k < 7; ++k){
        gload16(srcP[k], smem + dstO[k]);
        srcP[k] += stepO[k];
    }

    // LN2 -> B-operand fragments in registers
    bf16x8 afr[2][6];
    #pragma unroll
    for (int pt = 0; pt < 2; ++pt){
        int px = pt*16 + lo;
        float xv[48];
        float s = 0.f, s2 = 0.f;
        #pragma unroll
        for (int ks = 0; ks < 6; ++ks)
            #pragma unroll
            for (int j = 0; j < 8; ++j){
                float v = iob[(size_t)(ks*32 + hi*8 + j)*HW + px];
                xv[ks*8 + j] = v; s += v; s2 += v*v;
            }
        s  += __shfl_xor(s, 16);  s  += __shfl_xor(s, 32);
        s2 += __shfl_xor(s2, 16); s2 += __shfl_xor(s2, 32);
        float mean = s * (1.f/192.f);
        float rstd = rsqrtf(s2 * (1.f/192.f) - mean*mean + 1e-6f);
        #pragma unroll
        for (int ks = 0; ks < 6; ++ks){
            bf16x8 pk;
            #pragma unroll
            for (int j = 0; j < 8; ++j){
                int c = ks*32 + hi*8 + j;
                pk[j] = (__bf16)((xv[ks*8 + j] - mean) * rstd * lw[c] + lb[c]);
            }
            afr[pt][ks] = pk;
        }
    }
    __syncthreads();   // chunk 0 staged (barrier drains vmcnt)

    f32x4 acc2[12][2];
    #pragma unroll
    for (int nt2 = 0; nt2 < 12; ++nt2){
        acc2[nt2][0] = (f32x4){0.f,0.f,0.f,0.f};
        acc2[nt2][1] = (f32x4){0.f,0.f,0.f,0.f};
    }

    #pragma unroll 2
    for (int ch = 0; ch < 24; ++ch){
        const unsigned char* buf = smem + (ch & 1)*28672;
        unsigned char* nbuf = (unsigned char*)smem + ((ch & 1)^1)*28672;
        if (ch < 23){
            #pragma unroll
            for (int k = 0; k < 7; ++k){
                gload16(srcP[k], nbuf + dstO[k]);
                srcP[k] += stepO[k];
            }
        }
        // fc1: 32 hidden rows from LDS
        f32x4 a1[2][2];
        #pragma unroll
        for (int g = 0; g < 2; ++g){
            a1[g][0] = (f32x4){0.f,0.f,0.f,0.f};
            a1[g][1] = (f32x4){0.f,0.f,0.f,0.f};
        }
        #pragma unroll
        for (int ks = 0; ks < 6; ++ks){
            #pragma unroll
            for (int g = 0; g < 2; ++g){
                bf16x8 wf = *(const bf16x8*)(buf + (g*16 + lo)*400 + ks*64 + hi*16);
                a1[g][0] = __builtin_amdgcn_mfma_f32_16x16x32_bf16(wf, afr[0][ks], a1[g][0], 0, 0, 0);
                a1[g][1] = __builtin_amdgcn_mfma_f32_16x16x32_bf16(wf, afr[1][ks], a1[g][1], 0, 0, 0);
            }
        }
        int hb = ch*32;
        float bA[4], bB[4];
        #pragma unroll
        for (int r = 0; r < 4; ++r){
            bA[r] = b1[hb + hi*4 + r];
            bB[r] = b1[hb + 16 + hi*4 + r];
        }
        // bias + gelu + pack + in-wave transpose -> fc2 B-fragments (proven in R5)
        U8 b2f[2];
        #pragma unroll
        for (int pt = 0; pt < 2; ++pt){
            unsigned uA0 = pack2bf(gelu_f(a1[0][pt][0] + bA[0]), gelu_f(a1[0][pt][1] + bA[1]));
            unsigned uA1 = pack2bf(gelu_f(a1[0][pt][2] + bA[2]), gelu_f(a1[0][pt][3] + bA[3]));
            unsigned uB0 = pack2bf(gelu_f(a1[1][pt][0] + bB[0]), gelu_f(a1[1][pt][1] + bB[1]));
            unsigned uB1 = pack2bf(gelu_f(a1[1][pt][2] + bB[2]), gelu_f(a1[1][pt][3] + bB[3]));
            int s0 = lo + ((hi & 1) << 5);
            int s1 = s0 + 16;
            unsigned t0 = __shfl(uA0, s0), t1 = __shfl(uA1, s0);
            unsigned t2 = __shfl(uA0, s1), t3 = __shfl(uA1, s1);
            unsigned q0 = __shfl(uB0, s0), q1 = __shfl(uB1, s0);
            unsigned q2 = __shfl(uB0, s1), q3 = __shfl(uB1, s1);
            bool ub = (hi >= 2);
            b2f[pt].u[0] = ub ? q0 : t0;
            b2f[pt].u[1] = ub ? q1 : t1;
            b2f[pt].u[2] = ub ? q2 : t2;
            b2f[pt].u[3] = ub ? q3 : t3;
        }
        // fc2: 192 output rows from LDS, k = this 32-hidden chunk
        #pragma unroll
        for (int nt2 = 0; nt2 < 12; ++nt2){
            bf16x8 wf2 = *(const bf16x8*)(buf + 13312 + (nt2*16 + lo)*80 + hi*16);
            acc2[nt2][0] = __builtin_amdgcn_mfma_f32_16x16x32_bf16(wf2, b2f[0].v, acc2[nt2][0], 0, 0, 0);
            acc2[nt2][1] = __builtin_amdgcn_mfma_f32_16x16x32_bf16(wf2, b2f[1].v, acc2[nt2][1], 0, 0, 0);
        }
        __syncthreads();   // next chunk staged; all waves done reading buf
    }

    // epilogue: residual RMW
    #pragma unroll
    for (int nt2 = 0; nt2 < 12; ++nt2){
        #pragma unroll
        for (int r = 0; r < 4; ++r){
            int oc = nt2*16 + hi*4 + r;
            float bv = b2[oc];
            size_t idx = (size_t)oc*HW + lo;
            iob[idx]      += bv + acc2[nt2][0][r];
            iob[idx + 16] += bv + acc2[nt2][1][r];
        }
    }
}

extern "C" void kernel_launch(void* const* d_in, const int* in_sizes, int n_in,
                              void* d_out, int out_size, void* d_ws, size_t ws_size,
                              hipStream_t stream) {
    const float* x    = (const float*)d_in[0];
    const float* ln1w = (const float*)d_in[1];
    const float* ln1b = (const float*)d_in[2];
    const float* ipw  = (const float*)d_in[3];
    const float* ipb  = (const float*)d_in[4];
    const float* dwk  = (const float*)d_in[5];
    const float* lek  = (const float*)d_in[6];
    const float* dlg  = (const float*)d_in[7];
    const float* mlg  = (const float*)d_in[8];
    const float* isc  = (const float*)d_in[9];
    const float* bnw  = (const float*)d_in[10];
    const float* bnb  = (const float*)d_in[11];
    const float* opw  = (const float*)d_in[12];
    const float* opb  = (const float*)d_in[13];
    const float* ln2w = (const float*)d_in[14];
    const float* ln2b = (const float*)d_in[15];
    const float* f1w  = (const float*)d_in[16];
    const float* f1b  = (const float*)d_in[17];
    const float* f2w  = (const float*)d_in[18];
    const float* f2b  = (const float*)d_in[19];

    float* out = (float*)d_out;
    __bf16* bufP = (__bf16*)d_ws;                      // proj bf16
    __bf16* bufG = bufP + (size_t)NELEM;               // gate bf16
    float* bufM = (float*)(bufG + (size_t)NELEM);      // mixed f32
    float* part = bufM + (size_t)NELEM;
    float* bnp  = part + 2*NB*CH;
    __bf16* ipwb = (__bf16*)(bnp + 2*CH);
    __bf16* opwb = ipwb + (size_t)2*CH*CH;
    __bf16* w1b  = opwb + (size_t)CH*CH;
    __bf16* w2b  = w1b  + (size_t)HIDN*CH;

    k_cvt<<<(2*CH*CH + 255)/256, 256, 0, stream>>>(ipw, ipwb, 2*CH*CH);
    k_cvt<<<(CH*CH + 255)/256, 256, 0, stream>>>(opw, opwb, CH*CH);
    k_cvt<<<(HIDN*CH + 255)/256, 256, 0, stream>>>(f1w, w1b, HIDN*CH);
    k_cvt<<<(HIDN*CH + 255)/256, 256, 0, stream>>>(f2w, w2b, CH*HIDN);

    k_ln_inproj<<<1024, 256, 0, stream>>>(x, ln1w, ln1b, ipwb, ipb, bufP, bufG);
    k_spatial  <<<NB*CH, 256, 0, stream>>>(bufP, bufG, dwk, lek, dlg, mlg, isc, bufM, part);
    k_bn_final <<<1, 192, 0, stream>>>(part, bnw, bnb, bnp);
    k_outproj  <<<1024, 256, 0, stream>>>(bufM, bnp, opwb, opb, x, out);
    k_mlp      <<<512, 256, 0, stream>>>(ln2w, ln2b, w1b, f1b, w2b, f2b, out);
}